// Round 1
// baseline (19187.801 us; speedup 1.0000x reference)
//
#include <hip/hip_runtime.h>
#include <cstdio>

// HardLSTM (2 layers, T=512, B=32, IN=H=1024) on MI355X.
// Strategy: per-step eps folded via fp32 rowsums; bf16 MFMA 16x16x32 for
// gates = [x_t ; h] @ [W_ih ; W_hh]^T (fused K=2048); persistent kernel per
// layer with device-scope arrival-counter sync; W slice in LDS in
// fragment-linear order (conflict-free ds_read_b128); c carried in VGPRs.

#define T_STEPS 512
#define BATCH   32
#define HID     1024
#define NB      128     // blocks in recurrent kernel (1 wave each, 128KB LDS -> 1/CU, all resident)

typedef __bf16 bf16x8 __attribute__((ext_vector_type(8)));
typedef float  f32x4  __attribute__((ext_vector_type(4)));
typedef unsigned int u32x4 __attribute__((ext_vector_type(4)));

__device__ __forceinline__ unsigned short f2bf(float f){
  union { float f; unsigned u; } v; v.f = f;
  unsigned r = v.u + 0x7FFFu + ((v.u >> 16) & 1u);   // RNE
  return (unsigned short)(r >> 16);
}
__device__ __forceinline__ float bf2f(unsigned short h){
  union { unsigned u; float f; } v; v.u = ((unsigned)h) << 16; return v.f;
}

__device__ __forceinline__ bf16x8 ldg_frag(const unsigned short* p){
  u32x4 v = *reinterpret_cast<const u32x4*>(p);
  return __builtin_bit_cast(bf16x8, v);
}
__device__ __forceinline__ bf16x8 lds_frag(const unsigned short* ldsW, int fi, int lane){
  u32x4 v = *reinterpret_cast<const u32x4*>(ldsW + fi*512 + lane*8);
  return __builtin_bit_cast(bf16x8, v);
}

#define MFMA16 __builtin_amdgcn_mfma_f32_16x16x32_bf16

// ---------------- prep kernels ----------------

// Xbf[t][b][k] = bf16(x + 1)
__global__ void prep_x(const float* __restrict__ x, unsigned short* __restrict__ xbf, int n8){
  int idx = blockIdx.x*blockDim.x + threadIdx.x;
  int stride = gridDim.x*blockDim.x;
  for (int i = idx; i < n8; i += stride){
    const f32x4* p = reinterpret_cast<const f32x4*>(x + (size_t)i*8);
    f32x4 v0 = p[0], v1 = p[1];
    unsigned u0 = f2bf(v0[0]+1.f) | ((unsigned)f2bf(v0[1]+1.f)<<16);
    unsigned u1 = f2bf(v0[2]+1.f) | ((unsigned)f2bf(v0[3]+1.f)<<16);
    unsigned u2 = f2bf(v1[0]+1.f) | ((unsigned)f2bf(v1[1]+1.f)<<16);
    unsigned u3 = f2bf(v1[2]+1.f) | ((unsigned)f2bf(v1[3]+1.f)<<16);
    u32x4 cv = {u0,u1,u2,u3};
    *reinterpret_cast<u32x4*>(xbf + (size_t)i*8) = cv;
  }
}

// out[t] = mean(src[t][..32768..]) + add   (fp32 source)
__global__ void reduce_mean_f32(const float* __restrict__ src, float* __restrict__ out, float add){
  __shared__ float red[256];
  int t = blockIdx.x, tid = threadIdx.x;
  const float* p = src + (size_t)t*32768;
  float s = 0.f;
  for (int i = tid; i < 32768; i += 256) s += p[i];
  red[tid] = s; __syncthreads();
  for (int o = 128; o > 0; o >>= 1){ if (tid < o) red[tid] += red[tid+o]; __syncthreads(); }
  if (tid == 0) out[t] = red[0]*(1.f/32768.f) + add;
}

// out[t] = mean(src[t][..32768..]) + add   (bf16 source)
__global__ void reduce_mean_bf16(const unsigned short* __restrict__ src, float* __restrict__ out, float add){
  __shared__ float red[256];
  int t = blockIdx.x, tid = threadIdx.x;
  const unsigned short* p = src + (size_t)t*32768;
  float s = 0.f;
  for (int i = tid; i < 32768; i += 256) s += bf2f(p[i]);
  red[tid] = s; __syncthreads();
  for (int o = 128; o > 0; o >>= 1){ if (tid < o) red[tid] += red[tid+o]; __syncthreads(); }
  if (tid == 0) out[t] = red[0]*(1.f/32768.f) + add;
}

// rs[L*4096+n] = rowsum(Wih_L[n]) + rowsum(Whh_L[n]); bias = b_ih+b_hh. One wave per (L,n).
__global__ void prep_rs(const float* __restrict__ Wih0, const float* __restrict__ Whh0,
                        const float* __restrict__ Wih1, const float* __restrict__ Whh1,
                        const float* __restrict__ bih0, const float* __restrict__ bhh0,
                        const float* __restrict__ bih1, const float* __restrict__ bhh1,
                        float* __restrict__ rs, float* __restrict__ bias){
  int task = blockIdx.x*4 + (threadIdx.x >> 6);   // 8192 tasks
  int lane = threadIdx.x & 63;
  int L = task >> 12, n = task & 4095;
  const float* pi = (L ? Wih1 : Wih0) + (size_t)n*1024;
  const float* ph = (L ? Whh1 : Whh0) + (size_t)n*1024;
  float s = 0.f;
  #pragma unroll
  for (int e = 0; e < 16; ++e){ int k = lane + e*64; s += pi[k] + ph[k]; }
  #pragma unroll
  for (int m = 32; m; m >>= 1) s += __shfl_xor(s, m);
  if (lane == 0){
    rs[task]   = s;
    bias[task] = (L ? bih1[n] : bih0[n]) + (L ? bhh1[n] : bhh0[n]);
  }
}

__global__ void prep_hinit(const float* __restrict__ h0, unsigned short* __restrict__ hini){
  int i = blockIdx.x*256 + threadIdx.x;  // 65536 total
  hini[i] = f2bf(h0[i]);
}

// ---------------- persistent recurrent kernel (one layer) ----------------
// grid = 128 blocks x 64 threads. Block b owns columns j = b*8 .. b*8+7 of all
// 4 gates (W rows {g*1024 + j .. +7}, g=0..3 -> 32 rows x K=2048, 128KB LDS).
// Per step: acc(32x32) = [x_t ; h_{t-1}] @ Wslice^T via 256 MFMAs; x-half runs
// before the spin on arrive[t-1] to hide sync latency.
__global__ __launch_bounds__(64) void rec_kernel(
    const unsigned short* __restrict__ Xsrc,   // [T][32][1024] bf16 (layer input, eps NOT included)
    const unsigned short* __restrict__ Hini,   // [32][1024] bf16 initial h
    unsigned short* __restrict__ Ybf,          // bf16 output ring, stride 32768, mod ymod
    float* __restrict__ Yf32,                  // fp32 y output (layer 1 -> d_out), or nullptr
    const float* __restrict__ Wih, const float* __restrict__ Whh,  // [4096][1024] fp32
    const float* __restrict__ biasC, const float* __restrict__ rsC, // [4096]
    const float* __restrict__ eps,             // [512]
    const float* __restrict__ c0,              // [32][1024]
    float* __restrict__ hn_out, float* __restrict__ cn_out,         // [32][1024]
    unsigned int* __restrict__ arrive, int ymod)
{
  __shared__ unsigned short ldsW[65536];       // 128 KiB, fragment-linear: frag fi=kt*2+nt, 1KB each
  const int lane = threadIdx.x;
  const int jb   = blockIdx.x * 8;
  const int l15  = lane & 15;
  const int koff = (lane >> 4) << 3;           // A/B fragment k offset within 32-wide k-step
  const bool isLow = (l15 < 8);

  // ---- stage W slice into LDS (once), converting fp32->bf16, fragment-linear ----
  for (int fi = 0; fi < 128; ++fi){
    int ktg = fi >> 1, nt = fi & 1;
    int r = nt*16 + l15;                        // slice row 0..31
    int n = (r >> 3)*1024 + jb + (r & 7);       // gate = r>>3, joff = r&7
    int k0 = ktg*32 + koff;
    const float* src = (k0 < 1024) ? (Wih + (size_t)n*1024 + k0)
                                   : (Whh + (size_t)n*1024 + (k0 - 1024));
    f32x4 w0 = *reinterpret_cast<const f32x4*>(src);
    f32x4 w1 = *reinterpret_cast<const f32x4*>(src + 4);
    unsigned u0 = f2bf(w0[0]) | ((unsigned)f2bf(w0[1])<<16);
    unsigned u1 = f2bf(w0[2]) | ((unsigned)f2bf(w0[3])<<16);
    unsigned u2 = f2bf(w1[0]) | ((unsigned)f2bf(w1[1])<<16);
    unsigned u3 = f2bf(w1[2]) | ((unsigned)f2bf(w1[3])<<16);
    u32x4 cv = {u0,u1,u2,u3};
    *reinterpret_cast<u32x4*>(&ldsW[fi*512 + lane*8]) = cv;
  }

  // per-lane bias/rowsum for the two slice columns this lane owns in C/D layout
  int c0s = l15, c1s = 16 + l15;
  int n0 = (c0s >> 3)*1024 + jb + (c0s & 7);
  int n1 = (c1s >> 3)*1024 + jb + (c1s & 7);
  float bia0 = biasC[n0], rsv0 = rsC[n0];
  float bia1 = biasC[n1], rsv1 = rsC[n1];

  // c state in registers: lane holds c for (b = m*16 + (lane>>4)*4 + r, j = jb + (lane&7)),
  // duplicated across the lane/lane^8 pair (identical arithmetic).
  const int bq = (lane >> 4) * 4;
  const int jw = jb + (lane & 7);
  float creg[2][4];
  #pragma unroll
  for (int m = 0; m < 2; ++m)
    #pragma unroll
    for (int r = 0; r < 4; ++r)
      creg[m][r] = c0[(m*16 + bq + r)*1024 + jw];

  for (int t = 0; t < T_STEPS; ++t){
    float et = eps[t];
    f32x4 acc00 = {0.f,0.f,0.f,0.f}, acc01 = {0.f,0.f,0.f,0.f};
    f32x4 acc10 = {0.f,0.f,0.f,0.f}, acc11 = {0.f,0.f,0.f,0.f};

    // ---- x-projection half (no dependency on previous step) ----
    const unsigned short* A0 = Xsrc + (size_t)t*(BATCH*HID) + l15*HID + koff;
    #pragma unroll 4
    for (int kt = 0; kt < 32; ++kt){
      bf16x8 a0 = ldg_frag(A0 + kt*32);
      bf16x8 a1 = ldg_frag(A0 + 16*HID + kt*32);
      bf16x8 b0 = lds_frag(ldsW, kt*2 + 0, lane);
      bf16x8 b1 = lds_frag(ldsW, kt*2 + 1, lane);
      acc00 = MFMA16(a0, b0, acc00, 0, 0, 0);
      acc01 = MFMA16(a0, b1, acc01, 0, 0, 0);
      acc10 = MFMA16(a1, b0, acc10, 0, 0, 0);
      acc11 = MFMA16(a1, b1, acc11, 0, 0, 0);
    }

    // ---- wait for h_{t-1} to be fully published ----
    if (t > 0){
      while (__hip_atomic_load(arrive + (t-1), __ATOMIC_ACQUIRE, __HIP_MEMORY_SCOPE_AGENT) < NB) {}
    }
    const unsigned short* Ah = (t == 0) ? Hini
                              : (Ybf + (size_t)((t-1) % ymod)*(BATCH*HID));
    const unsigned short* A0h = Ah + l15*HID + koff;

    // ---- h-projection half ----
    #pragma unroll 4
    for (int kt = 0; kt < 32; ++kt){
      bf16x8 a0 = ldg_frag(A0h + kt*32);
      bf16x8 a1 = ldg_frag(A0h + 16*HID + kt*32);
      bf16x8 b0 = lds_frag(ldsW, (32+kt)*2 + 0, lane);
      bf16x8 b1 = lds_frag(ldsW, (32+kt)*2 + 1, lane);
      acc00 = MFMA16(a0, b0, acc00, 0, 0, 0);
      acc01 = MFMA16(a0, b1, acc01, 0, 0, 0);
      acc10 = MFMA16(a1, b0, acc10, 0, 0, 0);
      acc11 = MFMA16(a1, b1, acc11, 0, 0, 0);
    }

    // ---- epilogue: gates -> activations -> c/h update ----
    // C/D layout: col = lane&15 (slice col), row b = m*16 + (lane>>4)*4 + reg.
    // nt0 cols: 0..7 = i@j, 8..15 = f@j ; nt1 cols: 16..23 = g@j, 24..31 = o@j.
    #pragma unroll
    for (int m = 0; m < 2; ++m){
      f32x4 ga = m ? acc10 : acc00;   // i or f
      f32x4 gb = m ? acc11 : acc01;   // g or o
      #pragma unroll
      for (int r = 0; r < 4; ++r){
        float g0 = ga[r] + bia0 + et*rsv0;
        float g1 = gb[r] + bia1 + et*rsv1;
        float p0 = __shfl_xor(g0, 8);
        float p1 = __shfl_xor(g1, 8);
        float iv = isLow ? g0 : p0;
        float fv = isLow ? p0 : g0;
        float gv = isLow ? g1 : p1;
        float ov = isLow ? p1 : g1;
        iv = fminf(fmaxf(0.2f*iv + 0.5f, 0.f), 1.f);
        fv = fminf(fmaxf(0.2f*fv + 0.5f, 0.f), 1.f);
        gv = fminf(fmaxf(gv, -1.f), 1.f);
        ov = fminf(fmaxf(0.2f*ov + 0.5f, 0.f), 1.f);
        float cc = fv*(creg[m][r] + et) + iv*gv;
        creg[m][r] = cc;
        float hy = ov * fminf(fmaxf(cc, -1.f), 1.f);
        if (isLow){
          int b = m*16 + bq + r;
          Ybf[(size_t)(t % ymod)*(BATCH*HID) + b*HID + jw] = f2bf(hy);
          if (Yf32) Yf32[((size_t)t*BATCH + b)*HID + jw] = hy;
          if (t == T_STEPS-1){
            hn_out[b*HID + jw] = hy;
            cn_out[b*HID + jw] = cc;
          }
        }
      }
    }

    // ---- publish this step (release covers the whole wave's stores) ----
    if (lane == 0)
      __hip_atomic_fetch_add(arrive + t, 1u, __ATOMIC_RELEASE, __HIP_MEMORY_SCOPE_AGENT);
  }
}

// ---------------- host ----------------

extern "C" void kernel_launch(void* const* d_in, const int* in_sizes, int n_in,
                              void* d_out, int out_size, void* d_ws, size_t ws_size,
                              hipStream_t stream)
{
  const float* x    = (const float*)d_in[0];
  const float* h0   = (const float*)d_in[1];
  const float* c0   = (const float*)d_in[2];
  const float* Wih0 = (const float*)d_in[3];
  const float* Whh0 = (const float*)d_in[4];
  const float* bih0 = (const float*)d_in[5];
  const float* bhh0 = (const float*)d_in[6];
  const float* Wih1 = (const float*)d_in[7];
  const float* Whh1 = (const float*)d_in[8];
  const float* bih1 = (const float*)d_in[9];
  const float* bhh1 = (const float*)d_in[10];
  float* out = (float*)d_out;

  char* ws = (char*)d_ws;
  size_t off = 0;
  auto alloc = [&](size_t bytes)->char* {
    char* p = ws + off; off += (bytes + 255) & ~(size_t)255; return p;
  };
  unsigned short* Xbf  = (unsigned short*)alloc((size_t)T_STEPS*BATCH*HID*2); // 32MB
  unsigned short* Ybf0 = (unsigned short*)alloc((size_t)T_STEPS*BATCH*HID*2); // 32MB
  unsigned short* Yb1  = (unsigned short*)alloc((size_t)2*BATCH*HID*2);
  unsigned short* Hini = (unsigned short*)alloc((size_t)2*BATCH*HID*2);
  float* eps0 = (float*)alloc(T_STEPS*4);
  float* eps1 = (float*)alloc(T_STEPS*4);
  float* bias = (float*)alloc(2*4096*4);
  float* rs   = (float*)alloc(2*4096*4);
  unsigned int* arr = (unsigned int*)alloc(2*T_STEPS*4);
  if (off > ws_size)
    fprintf(stderr, "HardLSTM: ws too small, need %zu have %zu\n", off, ws_size);

  hipMemsetAsync(arr, 0, 2*T_STEPS*4, stream);
  prep_x<<<4096, 256, 0, stream>>>(x, Xbf, (T_STEPS*BATCH*HID)/8);
  reduce_mean_f32<<<T_STEPS, 256, 0, stream>>>(x, eps0, 1.0f);   // eps0 = mean(x_t)+1
  prep_rs<<<2048, 256, 0, stream>>>(Wih0, Whh0, Wih1, Whh1, bih0, bhh0, bih1, bhh1, rs, bias);
  prep_hinit<<<256, 256, 0, stream>>>(h0, Hini);

  float* hnOut = out + (size_t)T_STEPS*BATCH*HID;           // [2][32][1024]
  float* cnOut = hnOut + 2*BATCH*HID;                       // [2][32][1024]

  // layer 0
  rec_kernel<<<NB, 64, 0, stream>>>(Xbf, Hini, Ybf0, nullptr,
      Wih0, Whh0, bias, rs, eps0, c0, hnOut, cnOut, arr, T_STEPS);
  // eps for layer 1 = mean(y0_t)
  reduce_mean_bf16<<<T_STEPS, 256, 0, stream>>>(Ybf0, eps1, 0.0f);
  // layer 1
  rec_kernel<<<NB, 64, 0, stream>>>(Ybf0, Hini + BATCH*HID, Yb1, out,
      Wih1, Whh1, bias + 4096, rs + 4096, eps1, c0 + BATCH*HID,
      hnOut + BATCH*HID, cnOut + BATCH*HID, arr + T_STEPS, 2);
}

// Round 2
// 9454.117 us; speedup vs baseline: 2.0296x; 2.0296x over previous
//
#include <hip/hip_runtime.h>
#include <cstdio>

// HardLSTM (2 layers, T=512, B=32, IN=H=1024) on MI355X.
// Round 2: kill the cross-XCD cache-flush sync. All cross-block state (h ring,
// flags, eps partial sums) moves through the LLC via relaxed agent-scope
// atomics (no buffer_wbl2 / buffer_inv anywhere in the loop). Both layers are
// fused in one 256-block persistent kernel (1 block/CU); layer 1 pipelines one
// step behind layer 0. eps1 via deterministic fixed-point atomic adds.

#define T_STEPS 512
#define BATCH   32
#define HID     1024
#define NB      128     // blocks per layer

typedef __bf16 bf16x8 __attribute__((ext_vector_type(8)));
typedef float  f32x4  __attribute__((ext_vector_type(4)));
typedef float  f32x2  __attribute__((ext_vector_type(2)));
typedef unsigned int u32x4 __attribute__((ext_vector_type(4)));

__device__ __forceinline__ unsigned short f2bf(float f){
  union { float f; unsigned u; } v; v.f = f;
  unsigned r = v.u + 0x7FFFu + ((v.u >> 16) & 1u);   // RNE
  return (unsigned short)(r >> 16);
}

__device__ __forceinline__ bf16x8 ldg_frag(const unsigned short* p){
  u32x4 v = *reinterpret_cast<const u32x4*>(p);
  return __builtin_bit_cast(bf16x8, v);
}
// LLC-coherent 16B fragment load: two relaxed agent-scope u64 atomic loads.
// Bypasses (possibly stale) L1/L2; compiler tracks vmcnt normally so these
// pipeline like plain loads.
__device__ __forceinline__ bf16x8 ldA(const unsigned short* p){
  const unsigned long long* q = reinterpret_cast<const unsigned long long*>(p);
  unsigned long long v0 = __hip_atomic_load(q,     __ATOMIC_RELAXED, __HIP_MEMORY_SCOPE_AGENT);
  unsigned long long v1 = __hip_atomic_load(q + 1, __ATOMIC_RELAXED, __HIP_MEMORY_SCOPE_AGENT);
  union { unsigned long long u[2]; bf16x8 f; } w; w.u[0] = v0; w.u[1] = v1; return w.f;
}
__device__ __forceinline__ bf16x8 lds_frag(const unsigned short* ldsW, int fi, int lane){
  u32x4 v = *reinterpret_cast<const u32x4*>(ldsW + fi*512 + lane*8);
  return __builtin_bit_cast(bf16x8, v);
}

// Spin on 8 sub-counters (u32[8], read as 4 u64) until they sum to 128.
// Relaxed loads: no cache-maintenance instructions emitted.
__device__ __forceinline__ void spin8(const unsigned int* c){
  const unsigned long long* q = reinterpret_cast<const unsigned long long*>(c);
  while (true){
    unsigned long long a = __hip_atomic_load(q+0, __ATOMIC_RELAXED, __HIP_MEMORY_SCOPE_AGENT);
    unsigned long long b = __hip_atomic_load(q+1, __ATOMIC_RELAXED, __HIP_MEMORY_SCOPE_AGENT);
    unsigned long long d = __hip_atomic_load(q+2, __ATOMIC_RELAXED, __HIP_MEMORY_SCOPE_AGENT);
    unsigned long long e = __hip_atomic_load(q+3, __ATOMIC_RELAXED, __HIP_MEMORY_SCOPE_AGENT);
    unsigned long long s = a + b + d + e;               // per-counter <= 16, no carry across halves
    if ((unsigned)(s >> 32) + (unsigned)s >= 128u) break;
    __builtin_amdgcn_s_sleep(1);
  }
  asm volatile("" ::: "memory");   // no hoisting of data loads above the spin
}

#define MFMA16 __builtin_amdgcn_mfma_f32_16x16x32_bf16

// ---------------- prep kernels ----------------

__global__ void prep_x(const float* __restrict__ x, unsigned short* __restrict__ xbf, int n8){
  int idx = blockIdx.x*blockDim.x + threadIdx.x;
  int stride = gridDim.x*blockDim.x;
  for (int i = idx; i < n8; i += stride){
    const f32x4* p = reinterpret_cast<const f32x4*>(x + (size_t)i*8);
    f32x4 v0 = p[0], v1 = p[1];
    unsigned u0 = f2bf(v0[0]+1.f) | ((unsigned)f2bf(v0[1]+1.f)<<16);
    unsigned u1 = f2bf(v0[2]+1.f) | ((unsigned)f2bf(v0[3]+1.f)<<16);
    unsigned u2 = f2bf(v1[0]+1.f) | ((unsigned)f2bf(v1[1]+1.f)<<16);
    unsigned u3 = f2bf(v1[2]+1.f) | ((unsigned)f2bf(v1[3]+1.f)<<16);
    u32x4 cv = {u0,u1,u2,u3};
    *reinterpret_cast<u32x4*>(xbf + (size_t)i*8) = cv;
  }
}

__global__ void reduce_mean_f32(const float* __restrict__ src, float* __restrict__ out, float add){
  __shared__ float red[256];
  int t = blockIdx.x, tid = threadIdx.x;
  const float* p = src + (size_t)t*32768;
  float s = 0.f;
  for (int i = tid; i < 32768; i += 256) s += p[i];
  red[tid] = s; __syncthreads();
  for (int o = 128; o > 0; o >>= 1){ if (tid < o) red[tid] += red[tid+o]; __syncthreads(); }
  if (tid == 0) out[t] = red[0]*(1.f/32768.f) + add;
}

__global__ void prep_rs(const float* __restrict__ Wih0, const float* __restrict__ Whh0,
                        const float* __restrict__ Wih1, const float* __restrict__ Whh1,
                        const float* __restrict__ bih0, const float* __restrict__ bhh0,
                        const float* __restrict__ bih1, const float* __restrict__ bhh1,
                        float* __restrict__ rs, float* __restrict__ bias){
  int task = blockIdx.x*4 + (threadIdx.x >> 6);   // 8192 tasks
  int lane = threadIdx.x & 63;
  int L = task >> 12, n = task & 4095;
  const float* pi = (L ? Wih1 : Wih0) + (size_t)n*1024;
  const float* ph = (L ? Whh1 : Whh0) + (size_t)n*1024;
  float s = 0.f;
  #pragma unroll
  for (int e = 0; e < 16; ++e){ int k = lane + e*64; s += pi[k] + ph[k]; }
  #pragma unroll
  for (int m = 32; m; m >>= 1) s += __shfl_xor(s, m);
  if (lane == 0){
    rs[task]   = s;
    bias[task] = (L ? bih1[n] : bih0[n]) + (L ? bhh1[n] : bhh0[n]);
  }
}

__global__ void prep_hinit(const float* __restrict__ h0, unsigned short* __restrict__ hini){
  int i = blockIdx.x*256 + threadIdx.x;  // 65536 total = both layers
  hini[i] = f2bf(h0[i]);
}

// ---------------- fused persistent recurrent kernel (both layers) ----------------
// grid = 256 x 64. Blocks 0..127: layer 0; 128..255: layer 1 (pipelined 1 step
// behind). Block owns 8 h-columns x 4 gates (32 W rows x K=2048 -> 128KB LDS).
__global__ __launch_bounds__(64) void rec_fused(
    const unsigned short* __restrict__ Xbf,    // [512][32][1024] bf16 (x+1)
    const unsigned short* __restrict__ Hini,   // [2][32][1024] bf16
    unsigned short* __restrict__ Ring0,        // [512][32768] layer-0 h (= y0)
    unsigned short* __restrict__ Ring1,        // [8][32768]   layer-1 h
    float* __restrict__ out,                   // y1[512*32768] + hn[2][32768] + cn[2][32768]
    const float* __restrict__ Wih0, const float* __restrict__ Whh0,
    const float* __restrict__ Wih1, const float* __restrict__ Whh1,
    const float* __restrict__ biasC, const float* __restrict__ rsC,   // [2*4096]
    const float* __restrict__ eps0,            // [512]
    const float* __restrict__ c0,              // [2][32][1024]
    unsigned int* __restrict__ arr0, unsigned int* __restrict__ arr1, // [512*8]
    unsigned long long* __restrict__ epsAcc)   // [512] fixed-point sum(y0_t) * 2^16
{
  __shared__ unsigned short ldsW[65536];       // fragment-linear, 1KB per fragment
  const int lane = threadIdx.x;
  const int L    = blockIdx.x >> 7;
  const int bid  = blockIdx.x & 127;
  const int jb   = bid * 8;
  const int l15  = lane & 15;
  const int koff = (lane >> 4) << 3;
  const bool isLow = (l15 < 8);

  const float* Wih = L ? Wih1 : Wih0;
  const float* Whh = L ? Whh1 : Whh0;

  // ---- stage W slice into LDS (fp32 -> bf16, fragment-linear) ----
  for (int fi = 0; fi < 128; ++fi){
    int ktg = fi >> 1, nt = fi & 1;
    int r = nt*16 + l15;
    int n = (r >> 3)*1024 + jb + (r & 7);
    int k0 = ktg*32 + koff;
    const float* src = (k0 < 1024) ? (Wih + (size_t)n*1024 + k0)
                                   : (Whh + (size_t)n*1024 + (k0 - 1024));
    f32x4 w0 = *reinterpret_cast<const f32x4*>(src);
    f32x4 w1 = *reinterpret_cast<const f32x4*>(src + 4);
    unsigned u0 = f2bf(w0[0]) | ((unsigned)f2bf(w0[1])<<16);
    unsigned u1 = f2bf(w0[2]) | ((unsigned)f2bf(w0[3])<<16);
    unsigned u2 = f2bf(w1[0]) | ((unsigned)f2bf(w1[1])<<16);
    unsigned u3 = f2bf(w1[2]) | ((unsigned)f2bf(w1[3])<<16);
    u32x4 cv = {u0,u1,u2,u3};
    *reinterpret_cast<u32x4*>(&ldsW[fi*512 + lane*8]) = cv;
  }

  int c0s = l15, c1s = 16 + l15;
  int n0 = L*4096 + (c0s >> 3)*1024 + jb + (c0s & 7);
  int n1 = L*4096 + (c1s >> 3)*1024 + jb + (c1s & 7);
  float bia0 = biasC[n0], rsv0 = rsC[n0];
  float bia1 = biasC[n1], rsv1 = rsC[n1];

  const int bq = (lane >> 4) * 4;
  const int jw = jb + (lane & 7);
  float creg[2][4];
  #pragma unroll
  for (int m = 0; m < 2; ++m)
    #pragma unroll
    for (int r = 0; r < 4; ++r)
      creg[m][r] = c0[L*32768 + (m*16 + bq + r)*1024 + jw];

  float* outHn = out + 16777216 + L*32768;
  float* outCn = out + 16777216 + 65536 + L*32768;

  for (int t = 0; t < T_STEPS; ++t){
    f32x4 acc00 = {0.f,0.f,0.f,0.f}, acc01 = {0.f,0.f,0.f,0.f};
    f32x4 acc10 = {0.f,0.f,0.f,0.f}, acc11 = {0.f,0.f,0.f,0.f};
    float et;

    if (L == 0){
      // x-projection (independent) BEFORE the spin — hides peer latency
      const unsigned short* A0 = Xbf + (size_t)t*32768 + l15*HID + koff;
      #pragma unroll 4
      for (int kt = 0; kt < 32; ++kt){
        bf16x8 a0 = ldg_frag(A0 + kt*32);
        bf16x8 a1 = ldg_frag(A0 + 16*HID + kt*32);
        bf16x8 b0 = lds_frag(ldsW, kt*2 + 0, lane);
        bf16x8 b1 = lds_frag(ldsW, kt*2 + 1, lane);
        acc00 = MFMA16(a0, b0, acc00, 0, 0, 0);
        acc01 = MFMA16(a0, b1, acc01, 0, 0, 0);
        acc10 = MFMA16(a1, b0, acc10, 0, 0, 0);
        acc11 = MFMA16(a1, b1, acc11, 0, 0, 0);
      }
      et = eps0[t];
      if (t > 0) spin8(arr0 + (t-1)*8);
      const unsigned short* Ah = ((t == 0) ? Hini : Ring0 + (size_t)(t-1)*32768)
                                 + l15*HID + koff;
      #pragma unroll 4
      for (int kt = 0; kt < 32; ++kt){
        bf16x8 a0 = ldA(Ah + kt*32);
        bf16x8 a1 = ldA(Ah + 16*HID + kt*32);
        bf16x8 b0 = lds_frag(ldsW, (32+kt)*2 + 0, lane);
        bf16x8 b1 = lds_frag(ldsW, (32+kt)*2 + 1, lane);
        acc00 = MFMA16(a0, b0, acc00, 0, 0, 0);
        acc01 = MFMA16(a0, b1, acc01, 0, 0, 0);
        acc10 = MFMA16(a1, b0, acc10, 0, 0, 0);
        acc11 = MFMA16(a1, b1, acc11, 0, 0, 0);
      }
    } else {
      // layer 1: own-h half first (own-layer flags run ~in lockstep)
      if (t > 0) spin8(arr1 + (t-1)*8);
      const unsigned short* Ah = ((t == 0) ? Hini + 32768 : Ring1 + (size_t)((t-1)&7)*32768)
                                 + l15*HID + koff;
      #pragma unroll 4
      for (int kt = 0; kt < 32; ++kt){
        bf16x8 a0 = ldA(Ah + kt*32);
        bf16x8 a1 = ldA(Ah + 16*HID + kt*32);
        bf16x8 b0 = lds_frag(ldsW, (32+kt)*2 + 0, lane);
        bf16x8 b1 = lds_frag(ldsW, (32+kt)*2 + 1, lane);
        acc00 = MFMA16(a0, b0, acc00, 0, 0, 0);
        acc01 = MFMA16(a0, b1, acc01, 0, 0, 0);
        acc10 = MFMA16(a1, b0, acc10, 0, 0, 0);
        acc11 = MFMA16(a1, b1, acc11, 0, 0, 0);
      }
      spin8(arr0 + t*8);   // y0[t] + epsAcc[t] ready
      unsigned long long ea = __hip_atomic_load(epsAcc + t, __ATOMIC_RELAXED, __HIP_MEMORY_SCOPE_AGENT);
      et = (float)(long long)ea * (1.f/2147483648.f);   // / (2^16 * 32768)
      const unsigned short* Ay = Ring0 + (size_t)t*32768 + l15*HID + koff;
      #pragma unroll 4
      for (int kt = 0; kt < 32; ++kt){
        bf16x8 a0 = ldA(Ay + kt*32);
        bf16x8 a1 = ldA(Ay + 16*HID + kt*32);
        bf16x8 b0 = lds_frag(ldsW, kt*2 + 0, lane);
        bf16x8 b1 = lds_frag(ldsW, kt*2 + 1, lane);
        acc00 = MFMA16(a0, b0, acc00, 0, 0, 0);
        acc01 = MFMA16(a0, b1, acc01, 0, 0, 0);
        acc10 = MFMA16(a1, b0, acc10, 0, 0, 0);
        acc11 = MFMA16(a1, b1, acc11, 0, 0, 0);
      }
    }

    // ---- epilogue ----
    unsigned short* ring = L ? (Ring1 + (size_t)(t & 7)*32768) : (Ring0 + (size_t)t*32768);
    float psum = 0.f;
    #pragma unroll
    for (int m = 0; m < 2; ++m){
      f32x4 ga = m ? acc10 : acc00;   // cols 0..7 = i, 8..15 = f
      f32x4 gb = m ? acc11 : acc01;   // cols 16..23 = g, 24..31 = o
      #pragma unroll
      for (int r = 0; r < 4; ++r){
        float g0 = ga[r] + bia0 + et*rsv0;
        float g1 = gb[r] + bia1 + et*rsv1;
        float p0 = __shfl_xor(g0, 8);
        float p1 = __shfl_xor(g1, 8);
        float iv = isLow ? g0 : p0;
        float fv = isLow ? p0 : g0;
        float gv = isLow ? g1 : p1;
        float ov = isLow ? p1 : g1;
        iv = fminf(fmaxf(0.2f*iv + 0.5f, 0.f), 1.f);
        fv = fminf(fmaxf(0.2f*fv + 0.5f, 0.f), 1.f);
        gv = fminf(fmaxf(gv, -1.f), 1.f);
        ov = fminf(fmaxf(0.2f*ov + 0.5f, 0.f), 1.f);
        float cc = fv*(creg[m][r] + et) + iv*gv;
        creg[m][r] = cc;
        float hy = ov * fminf(fmaxf(cc, -1.f), 1.f);

        int b = m*16 + bq + r;
        unsigned short hu = f2bf(hy);
        unsigned nbv = __shfl_xor((unsigned)hu, 1);
        float    fnb = __shfl_xor(hy, 1);
        if (isLow){
          if (!(lane & 1)){
            // LLC write-through h publish (2 bf16 packed)
            __hip_atomic_store(reinterpret_cast<unsigned*>(ring + b*HID + jw),
                               ((unsigned)hu) | (nbv << 16),
                               __ATOMIC_RELAXED, __HIP_MEMORY_SCOPE_AGENT);
            if (L){
              f32x2 o2 = {hy, fnb};
              *reinterpret_cast<f32x2*>(out + (size_t)t*32768 + b*HID + jw) = o2;
            }
          }
          if (L == 0) psum += hy;
          if (t == T_STEPS-1){
            outHn[b*HID + jw] = hy;
            outCn[b*HID + jw] = cc;
          }
        }
      }
    }

    if (L == 0){
      #pragma unroll
      for (int mm = 32; mm; mm >>= 1) psum += __shfl_xor(psum, mm);
      if (lane == 0){
        long long q = llrintf(psum * 65536.f);   // deterministic fixed-point partial
        __hip_atomic_fetch_add(epsAcc + t, (unsigned long long)q,
                               __ATOMIC_RELAXED, __HIP_MEMORY_SCOPE_AGENT);
      }
    }

    // all h stores + eps partials at the coherence point before the flag
    asm volatile("s_waitcnt vmcnt(0)" ::: "memory");
    if (lane == 0)
      __hip_atomic_fetch_add((L ? arr1 : arr0) + t*8 + (bid & 7), 1u,
                             __ATOMIC_RELAXED, __HIP_MEMORY_SCOPE_AGENT);
  }
}

// ---------------- host ----------------

extern "C" void kernel_launch(void* const* d_in, const int* in_sizes, int n_in,
                              void* d_out, int out_size, void* d_ws, size_t ws_size,
                              hipStream_t stream)
{
  const float* x    = (const float*)d_in[0];
  const float* h0   = (const float*)d_in[1];
  const float* c0   = (const float*)d_in[2];
  const float* Wih0 = (const float*)d_in[3];
  const float* Whh0 = (const float*)d_in[4];
  const float* bih0 = (const float*)d_in[5];
  const float* bhh0 = (const float*)d_in[6];
  const float* Wih1 = (const float*)d_in[7];
  const float* Whh1 = (const float*)d_in[8];
  const float* bih1 = (const float*)d_in[9];
  const float* bhh1 = (const float*)d_in[10];
  float* out = (float*)d_out;

  char* ws = (char*)d_ws;
  size_t off = 0;
  auto alloc = [&](size_t bytes)->char* {
    char* p = ws + off; off += (bytes + 255) & ~(size_t)255; return p;
  };
  unsigned short* Xbf   = (unsigned short*)alloc((size_t)T_STEPS*BATCH*HID*2); // 32MB
  unsigned short* Ring0 = (unsigned short*)alloc((size_t)T_STEPS*BATCH*HID*2); // 32MB
  unsigned short* Ring1 = (unsigned short*)alloc((size_t)8*BATCH*HID*2);
  unsigned short* Hini  = (unsigned short*)alloc((size_t)2*BATCH*HID*2);
  float* eps0 = (float*)alloc(T_STEPS*4);
  float* bias = (float*)alloc(2*4096*4);
  float* rs   = (float*)alloc(2*4096*4);
  // flags + epsAcc contiguous so one memset re-zeros them per (graph-replayed) launch
  char* sync = alloc(T_STEPS*8*4*2 + T_STEPS*8);
  unsigned int*       arr0   = (unsigned int*)sync;
  unsigned int*       arr1   = (unsigned int*)(sync + T_STEPS*8*4);
  unsigned long long* epsAcc = (unsigned long long*)(sync + T_STEPS*8*4*2);
  if (off > ws_size)
    fprintf(stderr, "HardLSTM: ws too small, need %zu have %zu\n", off, ws_size);

  hipMemsetAsync(sync, 0, T_STEPS*8*4*2 + T_STEPS*8, stream);
  prep_x<<<4096, 256, 0, stream>>>(x, Xbf, (T_STEPS*BATCH*HID)/8);
  reduce_mean_f32<<<T_STEPS, 256, 0, stream>>>(x, eps0, 1.0f);   // eps0 = mean(x_t)+1
  prep_rs<<<2048, 256, 0, stream>>>(Wih0, Whh0, Wih1, Whh1, bih0, bhh0, bih1, bhh1, rs, bias);
  prep_hinit<<<256, 256, 0, stream>>>(h0, Hini);

  rec_fused<<<256, 64, 0, stream>>>(Xbf, Hini, Ring0, Ring1, out,
      Wih0, Whh0, Wih1, Whh1, bias, rs, eps0, c0, arr0, arr1, epsAcc);
}

// Round 3
// 8619.965 us; speedup vs baseline: 2.2260x; 1.0968x over previous
//
#include <hip/hip_runtime.h>
#include <cstdio>

// HardLSTM (2 layers, T=512, B=32, IN=H=1024) on MI355X.
// Round 3: contention-free cross-block sync. Per-block flags on private
// 128B cache lines, published with plain relaxed atomic stores (no RMW);
// spinners poll all 128 flags with ONE distributed gather (lane i -> flag i)
// + __all(). eps partial sums move to per-block fixed-point slots (no
// fetch_add anywhere in the loop). Layers fused & pipelined as in round 2.

#define T_STEPS 512
#define BATCH   32
#define HID     1024
#define NB      128     // blocks per layer

typedef __bf16 bf16x8 __attribute__((ext_vector_type(8)));
typedef float  f32x4  __attribute__((ext_vector_type(4)));
typedef float  f32x2  __attribute__((ext_vector_type(2)));
typedef unsigned int u32x4 __attribute__((ext_vector_type(4)));

__device__ __forceinline__ unsigned short f2bf(float f){
  union { float f; unsigned u; } v; v.f = f;
  unsigned r = v.u + 0x7FFFu + ((v.u >> 16) & 1u);   // RNE
  return (unsigned short)(r >> 16);
}

__device__ __forceinline__ bf16x8 ldg_frag(const unsigned short* p){
  u32x4 v = *reinterpret_cast<const u32x4*>(p);
  return __builtin_bit_cast(bf16x8, v);
}
// LLC-coherent 16B fragment load (bypasses possibly-stale L1/L2; pipelined).
__device__ __forceinline__ bf16x8 ldA(const unsigned short* p){
  const unsigned long long* q = reinterpret_cast<const unsigned long long*>(p);
  unsigned long long v0 = __hip_atomic_load(q,     __ATOMIC_RELAXED, __HIP_MEMORY_SCOPE_AGENT);
  unsigned long long v1 = __hip_atomic_load(q + 1, __ATOMIC_RELAXED, __HIP_MEMORY_SCOPE_AGENT);
  union { unsigned long long u[2]; bf16x8 f; } w; w.u[0] = v0; w.u[1] = v1; return w.f;
}
__device__ __forceinline__ bf16x8 lds_frag(const unsigned short* ldsW, int fi, int lane){
  u32x4 v = *reinterpret_cast<const u32x4*>(ldsW + fi*512 + lane*8);
  return __builtin_bit_cast(bf16x8, v);
}

// Wait until all 128 per-block flags (128B-strided) reach `target`.
// Lane i polls flag i and flag i+64: one distributed gather per iteration.
__device__ __forceinline__ void spin_flags(const unsigned int* f, unsigned target, int lane){
  const unsigned int* p0 = f + (size_t)lane*32;
  const unsigned int* p1 = f + (size_t)(lane+64)*32;
  while (true){
    unsigned a = __hip_atomic_load(p0, __ATOMIC_RELAXED, __HIP_MEMORY_SCOPE_AGENT);
    unsigned b = __hip_atomic_load(p1, __ATOMIC_RELAXED, __HIP_MEMORY_SCOPE_AGENT);
    if (__all((int)(a >= target && b >= target))) break;
    __builtin_amdgcn_s_sleep(1);
  }
  asm volatile("" ::: "memory");   // keep data loads below the spin
}

#define MFMA16 __builtin_amdgcn_mfma_f32_16x16x32_bf16

// ---------------- prep kernels ----------------

__global__ void prep_x(const float* __restrict__ x, unsigned short* __restrict__ xbf, int n8){
  int idx = blockIdx.x*blockDim.x + threadIdx.x;
  int stride = gridDim.x*blockDim.x;
  for (int i = idx; i < n8; i += stride){
    const f32x4* p = reinterpret_cast<const f32x4*>(x + (size_t)i*8);
    f32x4 v0 = p[0], v1 = p[1];
    unsigned u0 = f2bf(v0[0]+1.f) | ((unsigned)f2bf(v0[1]+1.f)<<16);
    unsigned u1 = f2bf(v0[2]+1.f) | ((unsigned)f2bf(v0[3]+1.f)<<16);
    unsigned u2 = f2bf(v1[0]+1.f) | ((unsigned)f2bf(v1[1]+1.f)<<16);
    unsigned u3 = f2bf(v1[2]+1.f) | ((unsigned)f2bf(v1[3]+1.f)<<16);
    u32x4 cv = {u0,u1,u2,u3};
    *reinterpret_cast<u32x4*>(xbf + (size_t)i*8) = cv;
  }
}

__global__ void reduce_mean_f32(const float* __restrict__ src, float* __restrict__ out, float add){
  __shared__ float red[256];
  int t = blockIdx.x, tid = threadIdx.x;
  const float* p = src + (size_t)t*32768;
  float s = 0.f;
  for (int i = tid; i < 32768; i += 256) s += p[i];
  red[tid] = s; __syncthreads();
  for (int o = 128; o > 0; o >>= 1){ if (tid < o) red[tid] += red[tid+o]; __syncthreads(); }
  if (tid == 0) out[t] = red[0]*(1.f/32768.f) + add;
}

__global__ void prep_rs(const float* __restrict__ Wih0, const float* __restrict__ Whh0,
                        const float* __restrict__ Wih1, const float* __restrict__ Whh1,
                        const float* __restrict__ bih0, const float* __restrict__ bhh0,
                        const float* __restrict__ bih1, const float* __restrict__ bhh1,
                        float* __restrict__ rs, float* __restrict__ bias){
  int task = blockIdx.x*4 + (threadIdx.x >> 6);   // 8192 tasks
  int lane = threadIdx.x & 63;
  int L = task >> 12, n = task & 4095;
  const float* pi = (L ? Wih1 : Wih0) + (size_t)n*1024;
  const float* ph = (L ? Whh1 : Whh0) + (size_t)n*1024;
  float s = 0.f;
  #pragma unroll
  for (int e = 0; e < 16; ++e){ int k = lane + e*64; s += pi[k] + ph[k]; }
  #pragma unroll
  for (int m = 32; m; m >>= 1) s += __shfl_xor(s, m);
  if (lane == 0){
    rs[task]   = s;
    bias[task] = (L ? bih1[n] : bih0[n]) + (L ? bhh1[n] : bhh0[n]);
  }
}

__global__ void prep_hinit(const float* __restrict__ h0, unsigned short* __restrict__ hini){
  int i = blockIdx.x*256 + threadIdx.x;  // 65536 total = both layers
  hini[i] = f2bf(h0[i]);
}

// ---------------- fused persistent recurrent kernel (both layers) ----------------
// grid = 256 x 64. Blocks 0..127: layer 0; 128..255: layer 1 (1 step behind).
// Block owns 8 h-columns x 4 gates (32 W rows x K=2048 -> 128KB LDS).
__global__ __launch_bounds__(64) void rec_fused(
    const unsigned short* __restrict__ Xbf,    // [512][32][1024] bf16 (x+1)
    const unsigned short* __restrict__ Hini,   // [2][32][1024] bf16
    unsigned short* __restrict__ Ring0,        // [512][32768] layer-0 h (= y0)
    unsigned short* __restrict__ Ring1,        // [8][32768]   layer-1 h
    float* __restrict__ out,                   // y1 + hn[2][32768] + cn[2][32768]
    const float* __restrict__ Wih0, const float* __restrict__ Whh0,
    const float* __restrict__ Wih1, const float* __restrict__ Whh1,
    const float* __restrict__ biasC, const float* __restrict__ rsC,   // [2*4096]
    const float* __restrict__ eps0,            // [512]
    const float* __restrict__ c0,              // [2][32][1024]
    unsigned int* __restrict__ flag0,          // [128] u32, 128B-strided
    unsigned int* __restrict__ flag1,          // [128] u32, 128B-strided
    int* __restrict__ epsP)                    // [512][128] i32, 128B-strided
{
  __shared__ unsigned short ldsW[65536];       // fragment-linear, 1KB per fragment
  const int lane = threadIdx.x;
  const int L    = blockIdx.x >> 7;
  const int bid  = blockIdx.x & 127;
  const int jb   = bid * 8;
  const int l15  = lane & 15;
  const int koff = (lane >> 4) << 3;
  const bool isLow = (l15 < 8);

  const float* Wih = L ? Wih1 : Wih0;
  const float* Whh = L ? Whh1 : Whh0;

  // ---- stage W slice into LDS (fp32 -> bf16, fragment-linear) ----
  for (int fi = 0; fi < 128; ++fi){
    int ktg = fi >> 1, nt = fi & 1;
    int r = nt*16 + l15;
    int n = (r >> 3)*1024 + jb + (r & 7);
    int k0 = ktg*32 + koff;
    const float* src = (k0 < 1024) ? (Wih + (size_t)n*1024 + k0)
                                   : (Whh + (size_t)n*1024 + (k0 - 1024));
    f32x4 w0 = *reinterpret_cast<const f32x4*>(src);
    f32x4 w1 = *reinterpret_cast<const f32x4*>(src + 4);
    unsigned u0 = f2bf(w0[0]) | ((unsigned)f2bf(w0[1])<<16);
    unsigned u1 = f2bf(w0[2]) | ((unsigned)f2bf(w0[3])<<16);
    unsigned u2 = f2bf(w1[0]) | ((unsigned)f2bf(w1[1])<<16);
    unsigned u3 = f2bf(w1[2]) | ((unsigned)f2bf(w1[3])<<16);
    u32x4 cv = {u0,u1,u2,u3};
    *reinterpret_cast<u32x4*>(&ldsW[fi*512 + lane*8]) = cv;
  }

  int c0s = l15, c1s = 16 + l15;
  int n0 = L*4096 + (c0s >> 3)*1024 + jb + (c0s & 7);
  int n1 = L*4096 + (c1s >> 3)*1024 + jb + (c1s & 7);
  float bia0 = biasC[n0], rsv0 = rsC[n0];
  float bia1 = biasC[n1], rsv1 = rsC[n1];

  const int bq = (lane >> 4) * 4;
  const int jw = jb + (lane & 7);
  float creg[2][4];
  #pragma unroll
  for (int m = 0; m < 2; ++m)
    #pragma unroll
    for (int r = 0; r < 4; ++r)
      creg[m][r] = c0[L*32768 + (m*16 + bq + r)*1024 + jw];

  float* outHn = out + 16777216 + L*32768;
  float* outCn = out + 16777216 + 65536 + L*32768;
  unsigned int* myflag = (L ? flag1 : flag0) + (size_t)bid*32;

  for (int t = 0; t < T_STEPS; ++t){
    f32x4 acc00 = {0.f,0.f,0.f,0.f}, acc01 = {0.f,0.f,0.f,0.f};
    f32x4 acc10 = {0.f,0.f,0.f,0.f}, acc11 = {0.f,0.f,0.f,0.f};
    float et;

    if (L == 0){
      // x-projection (independent) BEFORE the spin — hides peer latency
      const unsigned short* A0 = Xbf + (size_t)t*32768 + l15*HID + koff;
      #pragma unroll 4
      for (int kt = 0; kt < 32; ++kt){
        bf16x8 a0 = ldg_frag(A0 + kt*32);
        bf16x8 a1 = ldg_frag(A0 + 16*HID + kt*32);
        bf16x8 b0 = lds_frag(ldsW, kt*2 + 0, lane);
        bf16x8 b1 = lds_frag(ldsW, kt*2 + 1, lane);
        acc00 = MFMA16(a0, b0, acc00, 0, 0, 0);
        acc01 = MFMA16(a0, b1, acc01, 0, 0, 0);
        acc10 = MFMA16(a1, b0, acc10, 0, 0, 0);
        acc11 = MFMA16(a1, b1, acc11, 0, 0, 0);
      }
      et = eps0[t];
      if (t > 0) spin_flags(flag0, (unsigned)t, lane);
      const unsigned short* Ah = ((t == 0) ? Hini : Ring0 + (size_t)(t-1)*32768)
                                 + l15*HID + koff;
      #pragma unroll 4
      for (int kt = 0; kt < 32; ++kt){
        bf16x8 a0 = ldA(Ah + kt*32);
        bf16x8 a1 = ldA(Ah + 16*HID + kt*32);
        bf16x8 b0 = lds_frag(ldsW, (32+kt)*2 + 0, lane);
        bf16x8 b1 = lds_frag(ldsW, (32+kt)*2 + 1, lane);
        acc00 = MFMA16(a0, b0, acc00, 0, 0, 0);
        acc01 = MFMA16(a0, b1, acc01, 0, 0, 0);
        acc10 = MFMA16(a1, b0, acc10, 0, 0, 0);
        acc11 = MFMA16(a1, b1, acc11, 0, 0, 0);
      }
    } else {
      // layer 1: own-h half first (own-layer flags run ~in lockstep)
      if (t > 0) spin_flags(flag1, (unsigned)t, lane);
      const unsigned short* Ah = ((t == 0) ? Hini + 32768 : Ring1 + (size_t)((t-1)&7)*32768)
                                 + l15*HID + koff;
      #pragma unroll 4
      for (int kt = 0; kt < 32; ++kt){
        bf16x8 a0 = ldA(Ah + kt*32);
        bf16x8 a1 = ldA(Ah + 16*HID + kt*32);
        bf16x8 b0 = lds_frag(ldsW, (32+kt)*2 + 0, lane);
        bf16x8 b1 = lds_frag(ldsW, (32+kt)*2 + 1, lane);
        acc00 = MFMA16(a0, b0, acc00, 0, 0, 0);
        acc01 = MFMA16(a0, b1, acc01, 0, 0, 0);
        acc10 = MFMA16(a1, b0, acc10, 0, 0, 0);
        acc11 = MFMA16(a1, b1, acc11, 0, 0, 0);
      }
      spin_flags(flag0, (unsigned)(t+1), lane);   // y0[t] + eps partials ready
      // eps1[t] = sum of 128 per-block fixed-point partials (exact int sum)
      {
        const int* ep = epsP + (size_t)t*128*32;
        int pa = __hip_atomic_load(ep + (size_t)lane*32,      __ATOMIC_RELAXED, __HIP_MEMORY_SCOPE_AGENT);
        int pb = __hip_atomic_load(ep + (size_t)(lane+64)*32, __ATOMIC_RELAXED, __HIP_MEMORY_SCOPE_AGENT);
        int s = pa + pb;
        #pragma unroll
        for (int mm = 32; mm; mm >>= 1) s += __shfl_xor(s, mm);
        et = (float)s * 4.6566128730773926e-10f;   // / (2^16 * 32768)
      }
      const unsigned short* Ay = Ring0 + (size_t)t*32768 + l15*HID + koff;
      #pragma unroll 4
      for (int kt = 0; kt < 32; ++kt){
        bf16x8 a0 = ldA(Ay + kt*32);
        bf16x8 a1 = ldA(Ay + 16*HID + kt*32);
        bf16x8 b0 = lds_frag(ldsW, kt*2 + 0, lane);
        bf16x8 b1 = lds_frag(ldsW, kt*2 + 1, lane);
        acc00 = MFMA16(a0, b0, acc00, 0, 0, 0);
        acc01 = MFMA16(a0, b1, acc01, 0, 0, 0);
        acc10 = MFMA16(a1, b0, acc10, 0, 0, 0);
        acc11 = MFMA16(a1, b1, acc11, 0, 0, 0);
      }
    }

    // ---- epilogue ----
    unsigned short* ring = L ? (Ring1 + (size_t)(t & 7)*32768) : (Ring0 + (size_t)t*32768);
    float psum = 0.f;
    #pragma unroll
    for (int m = 0; m < 2; ++m){
      f32x4 ga = m ? acc10 : acc00;   // cols 0..7 = i, 8..15 = f
      f32x4 gb = m ? acc11 : acc01;   // cols 16..23 = g, 24..31 = o
      #pragma unroll
      for (int r = 0; r < 4; ++r){
        float g0 = ga[r] + bia0 + et*rsv0;
        float g1 = gb[r] + bia1 + et*rsv1;
        float p0 = __shfl_xor(g0, 8);
        float p1 = __shfl_xor(g1, 8);
        float iv = isLow ? g0 : p0;
        float fv = isLow ? p0 : g0;
        float gv = isLow ? g1 : p1;
        float ov = isLow ? p1 : g1;
        iv = fminf(fmaxf(0.2f*iv + 0.5f, 0.f), 1.f);
        fv = fminf(fmaxf(0.2f*fv + 0.5f, 0.f), 1.f);
        gv = fminf(fmaxf(gv, -1.f), 1.f);
        ov = fminf(fmaxf(0.2f*ov + 0.5f, 0.f), 1.f);
        float cc = fv*(creg[m][r] + et) + iv*gv;
        creg[m][r] = cc;
        float hy = ov * fminf(fmaxf(cc, -1.f), 1.f);

        int b = m*16 + bq + r;
        unsigned short hu = f2bf(hy);
        unsigned nbv = __shfl_xor((unsigned)hu, 1);
        float    fnb = __shfl_xor(hy, 1);
        if (isLow){
          if (!(lane & 1)){
            // LLC write-through h publish (2 bf16 packed)
            __hip_atomic_store(reinterpret_cast<unsigned*>(ring + b*HID + jw),
                               ((unsigned)hu) | (nbv << 16),
                               __ATOMIC_RELAXED, __HIP_MEMORY_SCOPE_AGENT);
            if (L){
              f32x2 o2 = {hy, fnb};
              *reinterpret_cast<f32x2*>(out + (size_t)t*32768 + b*HID + jw) = o2;
            }
          }
          if (L == 0) psum += hy;
          if (t == T_STEPS-1){
            outHn[b*HID + jw] = hy;
            outCn[b*HID + jw] = cc;
          }
        }
      }
    }

    if (L == 0){
      #pragma unroll
      for (int mm = 32; mm; mm >>= 1) psum += __shfl_xor(psum, mm);
      if (lane == 0){
        // deterministic fixed-point partial in this block's private line
        __hip_atomic_store(epsP + ((size_t)t*128 + bid)*32, (int)llrintf(psum * 65536.f),
                           __ATOMIC_RELAXED, __HIP_MEMORY_SCOPE_AGENT);
      }
    }

    // drain h stores + eps partial to the coherence point, then publish flag
    asm volatile("s_waitcnt vmcnt(0)" ::: "memory");
    if (lane == 0)
      __hip_atomic_store(myflag, (unsigned)(t+1),
                         __ATOMIC_RELAXED, __HIP_MEMORY_SCOPE_AGENT);
  }
}

// ---------------- host ----------------

extern "C" void kernel_launch(void* const* d_in, const int* in_sizes, int n_in,
                              void* d_out, int out_size, void* d_ws, size_t ws_size,
                              hipStream_t stream)
{
  const float* x    = (const float*)d_in[0];
  const float* h0   = (const float*)d_in[1];
  const float* c0   = (const float*)d_in[2];
  const float* Wih0 = (const float*)d_in[3];
  const float* Whh0 = (const float*)d_in[4];
  const float* bih0 = (const float*)d_in[5];
  const float* bhh0 = (const float*)d_in[6];
  const float* Wih1 = (const float*)d_in[7];
  const float* Whh1 = (const float*)d_in[8];
  const float* bih1 = (const float*)d_in[9];
  const float* bhh1 = (const float*)d_in[10];
  float* out = (float*)d_out;

  char* ws = (char*)d_ws;
  size_t off = 0;
  auto alloc = [&](size_t bytes)->char* {
    char* p = ws + off; off += (bytes + 255) & ~(size_t)255; return p;
  };
  unsigned short* Xbf   = (unsigned short*)alloc((size_t)T_STEPS*BATCH*HID*2); // 32MB
  unsigned short* Ring0 = (unsigned short*)alloc((size_t)T_STEPS*BATCH*HID*2); // 32MB
  unsigned short* Ring1 = (unsigned short*)alloc((size_t)8*BATCH*HID*2);
  unsigned short* Hini  = (unsigned short*)alloc((size_t)2*BATCH*HID*2);
  float* eps0 = (float*)alloc(T_STEPS*4);
  float* bias = (float*)alloc(2*4096*4);
  float* rs   = (float*)alloc(2*4096*4);
  // sync area: flag0[128 lines] + flag1[128 lines] + epsP[512*128 lines]
  char* sync = alloc(128*128*2 + (size_t)T_STEPS*128*128);
  unsigned int* flag0 = (unsigned int*)sync;
  unsigned int* flag1 = (unsigned int*)(sync + 128*128);
  int*          epsP  = (int*)(sync + 128*128*2);
  if (off > ws_size)
    fprintf(stderr, "HardLSTM: ws too small, need %zu have %zu\n", off, ws_size);

  // only the flags must be re-zeroed per launch (epsP fully rewritten in-kernel)
  hipMemsetAsync(sync, 0, 128*128*2, stream);
  prep_x<<<4096, 256, 0, stream>>>(x, Xbf, (T_STEPS*BATCH*HID)/8);
  reduce_mean_f32<<<T_STEPS, 256, 0, stream>>>(x, eps0, 1.0f);   // eps0 = mean(x_t)+1
  prep_rs<<<2048, 256, 0, stream>>>(Wih0, Whh0, Wih1, Whh1, bih0, bhh0, bih1, bhh1, rs, bias);
  prep_hinit<<<256, 256, 0, stream>>>(h0, Hini);

  rec_fused<<<256, 64, 0, stream>>>(Xbf, Hini, Ring0, Ring1, out,
      Wih0, Whh0, Wih1, Whh1, bias, rs, eps0, c0, flag0, flag1, epsP);
}